// Round 1
// baseline (103.677 us; speedup 1.0000x reference)
//
#include <hip/hip_runtime.h>
#include <math.h>

#define GRID_D 362
#define NKEYS  10000
#define EPSV   1e-8f

__global__ __launch_bounds__(256) void planner_kernel(
    const float* __restrict__ batch_x,   // [B, 362]
    const int*   __restrict__ batch_a,   // [B]
    const float* __restrict__ keys,      // [3, 10000, 6]
    const float* __restrict__ values,    // [3, 10000, 7]
    float* __restrict__ out_x,           // [B, 362]
    float* __restrict__ out_unc,         // [B]
    float* __restrict__ out_done)        // [B]
{
    const int b   = blockIdx.x;
    const int tid = threadIdx.x;
    constexpr int NT = 256;
    const float* x = batch_x + (size_t)b * GRID_D;

    __shared__ float s_sim[NKEYS];   // 40 KB
    __shared__ float s_redf[32];
    __shared__ int   s_redi[4];
    __shared__ float s_q[6];
    __shared__ int   s_cell[6];
    __shared__ float s_delta[6];
    __shared__ float s_max;

    // ---------- Phase A: argmax over 362 (first-index tie-break) ----------
    float bestv = -INFINITY;
    int   besti = 1 << 30;
    for (int i = tid; i < GRID_D; i += NT) {
        float v = x[i];
        if (v > bestv || (v == bestv && i < besti)) { bestv = v; besti = i; }
    }
    for (int off = 32; off > 0; off >>= 1) {
        float ov = __shfl_down(bestv, off);
        int   oi = __shfl_down(besti, off);
        if (ov > bestv || (ov == bestv && oi < besti)) { bestv = ov; besti = oi; }
    }
    const int wid = tid >> 6;
    if ((tid & 63) == 0) { s_redf[wid] = bestv; s_redi[wid] = besti; }
    __syncthreads();

    // ---------- Phase B: cells + normalized query (thread 0) ----------
    if (tid == 0) {
        float bv = s_redf[0]; int bi = s_redi[0];
        for (int w = 1; w < NT / 64; ++w) {
            float ov = s_redf[w]; int oi = s_redi[w];
            if (ov > bv || (ov == bv && oi < bi)) { bv = ov; bi = oi; }
        }
        const int ptr = bi;
        int cells[6];
        cells[0] = 0;
        cells[1] = ptr;
        cells[2] = min(max(ptr - 19, 1), GRID_D - 1);
        cells[3] = min(max(ptr + 19, 1), GRID_D - 1);
        cells[4] = min(max(ptr - 1,  1), GRID_D - 1);
        cells[5] = min(max(ptr + 1,  1), GRID_D - 1);
        float att[6], ss = 0.f;
        for (int j = 0; j < 6; ++j) { att[j] = x[cells[j]]; ss += att[j] * att[j]; }
        const float inv = 1.f / (sqrtf(ss) + EPSV);
        for (int j = 0; j < 6; ++j) { s_q[j] = att[j] * inv; s_cell[j] = cells[j]; }
    }
    __syncthreads();

    const int a = batch_a[b];
    const float* __restrict__ krow = keys   + (size_t)a * NKEYS * 6;
    const float* __restrict__ vrow = values + (size_t)a * NKEYS * 7;

    const float q0 = s_q[0], q1 = s_q[1], q2 = s_q[2],
                q3 = s_q[3], q4 = s_q[4], q5 = s_q[5];

    // ---------- Phase C1: similarities + running max ----------
    float lmax = -INFINITY;
    for (int n = tid; n < NKEYS; n += NT) {
        const float* k = krow + n * 6;          // 24 B rows -> float2-aligned
        float2 k01 = *(const float2*)(k);
        float2 k23 = *(const float2*)(k + 2);
        float2 k45 = *(const float2*)(k + 4);
        float dot = q0 * k01.x + q1 * k01.y + q2 * k23.x +
                    q3 * k23.y + q4 * k45.x + q5 * k45.y;
        float nn  = k01.x * k01.x + k01.y * k01.y + k23.x * k23.x +
                    k23.y * k23.y + k45.x * k45.x + k45.y * k45.y;
        float sim = dot / (sqrtf(nn) + EPSV);
        s_sim[n] = sim;
        lmax = fmaxf(lmax, sim);
    }
    for (int off = 32; off > 0; off >>= 1)
        lmax = fmaxf(lmax, __shfl_down(lmax, off));
    if ((tid & 63) == 0) s_redf[wid] = lmax;
    __syncthreads();
    if (tid == 0) {
        float m = s_redf[0];
        for (int w = 1; w < NT / 64; ++w) m = fmaxf(m, s_redf[w]);
        s_max = m;
    }
    __syncthreads();
    const float msim = s_max;

    // ---------- Phase C2: softmax numerator + weighted values ----------
    float vals[8];
#pragma unroll
    for (int q = 0; q < 8; ++q) vals[q] = 0.f;
    for (int n = tid; n < NKEYS; n += NT) {
        const float e = __expf(s_sim[n] - msim);
        const float* v = vrow + n * 7;
        vals[0] += e;
#pragma unroll
        for (int p = 0; p < 7; ++p) vals[1 + p] += e * v[p];
    }
    for (int off = 32; off > 0; off >>= 1)
#pragma unroll
        for (int q = 0; q < 8; ++q) vals[q] += __shfl_down(vals[q], off);
    if ((tid & 63) == 0)
#pragma unroll
        for (int q = 0; q < 8; ++q) s_redf[wid * 8 + q] = vals[q];
    __syncthreads();
    if (tid == 0) {
        float t[8];
#pragma unroll
        for (int q = 0; q < 8; ++q)
            t[q] = s_redf[q] + s_redf[8 + q] + s_redf[16 + q] + s_redf[24 + q];
        const float inv = 1.f / t[0];
        float pr[7];
#pragma unroll
        for (int p = 0; p < 7; ++p) pr[p] = t[1 + p] * inv;
        for (int j = 0; j < 6; ++j) s_delta[j] = pr[j];
        out_unc[b]  = -msim;
        out_done[b] = pr[6];
    }
    __syncthreads();

    // ---------- Phase D: scatter deltas (last j wins) + copy row ----------
    int   cells[6];
    float dels[6];
#pragma unroll
    for (int j = 0; j < 6; ++j) { cells[j] = s_cell[j]; dels[j] = s_delta[j]; }
    for (int c = tid; c < GRID_D; c += NT) {
        float add = 0.f;
#pragma unroll
        for (int j = 0; j < 6; ++j)
            if (cells[j] == c) add = dels[j];   // ascending j -> last write wins
        out_x[(size_t)b * GRID_D + c] = x[c] + add;
    }
}

extern "C" void kernel_launch(void* const* d_in, const int* in_sizes, int n_in,
                              void* d_out, int out_size, void* d_ws, size_t ws_size,
                              hipStream_t stream) {
    const float* batch_x = (const float*)d_in[0];
    const int*   batch_a = (const int*)d_in[1];
    const float* keys    = (const float*)d_in[2];
    const float* values  = (const float*)d_in[3];
    const int B = in_sizes[1];                 // 4096

    float* out      = (float*)d_out;
    float* out_x    = out;                      // B*GRID
    float* out_unc  = out + (size_t)B * GRID_D; // B
    float* out_done = out_unc + B;              // B

    planner_kernel<<<B, 256, 0, stream>>>(batch_x, batch_a, keys, values,
                                          out_x, out_unc, out_done);
}